// Round 5
// baseline (125.890 us; speedup 1.0000x reference)
//
#include <hip/hip_runtime.h>
#include <hip/hip_bf16.h>
#include <math.h>

// OHEM BCE-with-logits, shape (4,1,192,192,192) f32, scalar f32 output.
//
// R5: fully branch-free histogram pass. BOTH classes are histogrammed on the
// logit x (softplus is monotone): negatives -> bins [0,4096), positives ->
// bins [4096,8192). Per-bin softplus evaluation happens once per bin in the
// finalize kernel; within-bin error <= 2e-3 << 5.5e-2 tolerance.
// The global-atomic flush (512 contenders per address, cross-XCD RMW tail)
// is replaced by per-block private histogram slices (plain coalesced stores)
// + a 32-block tree-reduce kernel. No global atomics anywhere.

#define NB_NEG 4096
#define NB_TOT 8192
#define XOFF 8.0f
#define BIN_SCALE 256.0f        // (x+8)*256 -> [0, 4096)
#define INV_BIN 0.00390625f     // 1/256

extern "C" __global__ __launch_bounds__(1024) void ohem_pass1(
    const float* __restrict__ logits, const float* __restrict__ targets,
    unsigned int* __restrict__ g_part,
    int n8, int n_total)
{
    __shared__ unsigned int h[NB_TOT];   // 32 KiB
    for (int i = threadIdx.x; i < NB_TOT; i += 1024) h[i] = 0u;
    __syncthreads();

    const float4* L4 = (const float4*)logits;
    const float4* T4 = (const float4*)targets;
    const int stride = gridDim.x * blockDim.x;

    for (int i = blockIdx.x * blockDim.x + threadIdx.x; i < n8; i += stride) {
        float4 xa = L4[2 * i];
        float4 xb = L4[2 * i + 1];
        float4 ta = T4[2 * i];
        float4 tb = T4[2 * i + 1];
        float xs[8] = {xa.x, xa.y, xa.z, xa.w, xb.x, xb.y, xb.z, xb.w};
        float ts[8] = {ta.x, ta.y, ta.z, ta.w, tb.x, tb.y, tb.z, tb.w};
        #pragma unroll
        for (int j = 0; j < 8; ++j) {
            float f = fmaxf(fmaf(xs[j], BIN_SCALE, XOFF * BIN_SCALE), 0.0f);
            unsigned int bin = (unsigned int)f;
            bin = bin > NB_NEG - 1 ? NB_NEG - 1 : bin;
            bin += (ts[j] > 0.5f) ? NB_NEG : 0u;      // branchless class routing
            atomicAdd(&h[bin], 1u);                   // non-returning ds_add_u32
        }
    }
    // tail (n_total % 8) -- not hit for this shape, kept for safety
    if (blockIdx.x == 0) {
        for (int t = n8 * 8 + threadIdx.x; t < n_total; t += 1024) {
            float f = fmaxf(fmaf(logits[t], BIN_SCALE, XOFF * BIN_SCALE), 0.0f);
            unsigned int bin = (unsigned int)f;
            bin = bin > NB_NEG - 1 ? NB_NEG - 1 : bin;
            bin += (targets[t] > 0.5f) ? NB_NEG : 0u;
            atomicAdd(&h[bin], 1u);
        }
    }
    __syncthreads();

    // flush to this block's PRIVATE slice: plain coalesced stores, no atomics
    unsigned int* dst = g_part + (size_t)blockIdx.x * NB_TOT;
    for (int b = threadIdx.x; b < NB_TOT; b += 1024) dst[b] = h[b];
}

extern "C" __global__ __launch_bounds__(256) void ohem_reduce(
    const unsigned int* __restrict__ g_part, unsigned int* __restrict__ g_hist,
    int nb)
{
    int b = blockIdx.x * 256 + threadIdx.x;   // 0..8191, coalesced per wave
    unsigned int s = 0;
    for (int c = 0; c < nb; ++c) s += g_part[(size_t)c * NB_TOT + b];
    g_hist[b] = s;
}

__device__ __forceinline__ float softplus_acc(float v) {
    return fmaxf(v, 0.0f) + log1pf(expf(-fabsf(v)));
}

extern "C" __global__ __launch_bounds__(256) void ohem_finalize(
    const unsigned int* __restrict__ g_hist, float* __restrict__ out,
    int n_total)
{
    const int BPT = NB_NEG / 256; // 16 bins per thread
    __shared__ unsigned int sh_c[256];
    __shared__ float sh_s[256];
    __shared__ unsigned int suf_c[256];
    __shared__ float suf_s[256];
    __shared__ unsigned int sh_pc[256];
    __shared__ float sh_ps[256];
    __shared__ unsigned int tot_pc;
    __shared__ float tot_ps;

    int tid = threadIdx.x;

    // negative bins: per-bin total loss c * softplus(center)
    unsigned int lc[BPT];
    float lloss[BPT];
    unsigned int tc = 0;
    float tsum = 0.0f;
    #pragma unroll
    for (int j = 0; j < BPT; ++j) {
        int b = tid * BPT + j;
        unsigned int c = g_hist[b];
        lc[j] = c;
        float lb = 0.0f;
        if (c > 0) {
            float center = ((float)b + 0.5f) * INV_BIN - XOFF;
            lb = (float)c * softplus_acc(center);
        }
        lloss[j] = lb;
        tc += c;
        tsum += lb;
    }
    // positive bins: loss = softplus(-x)
    unsigned int pc = 0;
    float ps = 0.0f;
    #pragma unroll
    for (int j = 0; j < BPT; ++j) {
        int b = tid * BPT + j;
        unsigned int c = g_hist[NB_NEG + b];
        if (c > 0) {
            float center = ((float)b + 0.5f) * INV_BIN - XOFF;
            ps += (float)c * softplus_acc(-center);
            pc += c;
        }
    }
    sh_c[tid] = tc;  sh_s[tid] = tsum;
    sh_pc[tid] = pc; sh_ps[tid] = ps;
    __syncthreads();

    if (tid == 0) {
        unsigned int rc = 0; float rs = 0.0f;
        for (int i = 255; i >= 0; --i) {      // exclusive suffix totals
            suf_c[i] = rc; suf_s[i] = rs;
            rc += sh_c[i]; rs += sh_s[i];
        }
        unsigned int qc = 0; float qs = 0.0f;
        for (int i = 0; i < 256; ++i) { qc += sh_pc[i]; qs += sh_ps[i]; }
        tot_pc = qc; tot_ps = qs;
    }
    __syncthreads();

    unsigned int n_pos = tot_pc;
    unsigned int n_neg = (unsigned int)n_total - n_pos;
    float pos_mean = (n_pos > 0) ? (tot_ps / (float)n_pos) : 0.0f;

    if (n_neg == 0) {
        if (tid == 0) out[0] = pos_mean;
        return;
    }

    // k = max(1024, rint(0.1 * n_neg)), clamped to n_neg (RNE matches jnp.round)
    float nf = (float)n_neg;
    int k = (int)rintf(nf * 0.1f);
    if (k < 1024) k = 1024;
    if ((unsigned int)k > n_neg) k = (int)n_neg;

    // walk own chunk from the top bin down; exactly one (tid, j) crosses k
    unsigned int run_c = suf_c[tid];
    float run_s = suf_s[tid];
    #pragma unroll
    for (int j = BPT - 1; j >= 0; --j) {
        unsigned int c = lc[j];
        float lb = lloss[j];
        if (c > 0 && run_c < (unsigned int)k && run_c + c >= (unsigned int)k) {
            unsigned int m = (unsigned int)k - run_c;
            float neg_sum = run_s + (float)m * (lb / (float)c);
            float neg_mean = neg_sum / (float)k;
            out[0] = pos_mean + neg_mean;
        }
        run_c += c;
        run_s += lb;
    }
}

extern "C" void kernel_launch(void* const* d_in, const int* in_sizes, int n_in,
                              void* d_out, int out_size, void* d_ws, size_t ws_size,
                              hipStream_t stream) {
    const float* logits  = (const float*)d_in[0];
    const float* targets = (const float*)d_in[1];
    float* out = (float*)d_out;
    int n_total = in_sizes[0];
    int n8 = n_total / 8;

    // ws layout: [nb private histograms (nb*32KB)] [reduced histogram 32KB]
    const size_t slice = (size_t)NB_TOT * 4;
    int nb = 512;                              // 2 blocks/CU * 16 waves = full
    size_t need = (size_t)nb * slice + slice;
    if (ws_size < need) {
        nb = (int)((ws_size - slice) / slice);
        if (nb < 1) nb = 1;
    }
    unsigned int* g_part = (unsigned int*)d_ws;
    unsigned int* g_hist = g_part + (size_t)nb * NB_TOT;

    ohem_pass1<<<nb, 1024, 0, stream>>>(logits, targets, g_part, n8, n_total);
    ohem_reduce<<<NB_TOT / 256, 256, 0, stream>>>(g_part, g_hist, nb);
    ohem_finalize<<<1, 256, 0, stream>>>(g_hist, out, n_total);
}

// Round 6
// 92.182 us; speedup vs baseline: 1.3657x; 1.3657x over previous
//
#include <hip/hip_runtime.h>
#include <hip/hip_bf16.h>
#include <math.h>

// OHEM BCE-with-logits, shape (4,1,192,192,192) f32, scalar f32 output.
//
// R6: zero-LDS-atomic hot loop. Evidence R1-R5: time tracks ONLY the LDS
// atomic type/count (u64->u32 = 1.38x; occupancy/VALU/branch/flush changes =
// nothing) => scattered ds_add processes ~1 lane/cycle and is the floor.
// Fix: ballot-transpose register histogram. 256 bins on the logit x
// (softplus monotone => top-k selects on x). Per 64-element slot: 8 bin-bit
// ballots + 1 class ballot; each lane owns 8 bins (lane + 64*j, neg & pos)
// accumulated with mask-AND + popcount in VGPRs. Flush: 512 LDS atomics per
// BLOCK (not per element), 2KB private slice per block, parallel reduce.

typedef unsigned long long ull;
typedef unsigned int uint;

#define NBN 256          // negative bins
#define NBT 512          // neg + pos
#define BSCALE 16.0f     // bin = (x+8)*16 -> [0,256)
#define INVB 0.0625f
#define XOFF 8.0f
#define GRID1 1728
#define THREADS1 256

__device__ __forceinline__ uint bin_of(float x) {
    float f = fmaxf(fmaf(x, BSCALE, XOFF * BSCALE), 0.0f);
    uint b = (uint)f;
    return b > (NBN - 1) ? (NBN - 1) : b;
}

extern "C" __global__ __launch_bounds__(256, 4) void ohem_pass1(
    const float4* __restrict__ L4, const float4* __restrict__ T4,
    uint* __restrict__ g_part, int n4, int iters, int G)
{
    __shared__ uint hist[NBT];
    const int tid = threadIdx.x;
    hist[tid] = 0u;
    hist[tid + 256] = 0u;
    __syncthreads();

    const int lane = tid & 63;
    // complement masks: mask_i = m_i ^ ne_i selects lanes whose bin bit i
    // equals this lane's bit i
    const ull ne0 = (lane & 1)  ? 0ull : ~0ull;
    const ull ne1 = (lane & 2)  ? 0ull : ~0ull;
    const ull ne2 = (lane & 4)  ? 0ull : ~0ull;
    const ull ne3 = (lane & 8)  ? 0ull : ~0ull;
    const ull ne4 = (lane & 16) ? 0ull : ~0ull;
    const ull ne5 = (lane & 32) ? 0ull : ~0ull;

    uint cn0 = 0, cn1 = 0, cn2 = 0, cn3 = 0;
    uint cp0 = 0, cp1 = 0, cp2 = 0, cp3 = 0;

    const int g = blockIdx.x * 256 + tid;

#define SLOT(xv, tv, vld) {                                                  \
    uint b = (vld) ? bin_of(xv) : 0u;                                        \
    bool isp = (vld) && ((tv) > 0.5f);                                       \
    ull m0 = __ballot((b & 1u) != 0u);                                       \
    ull m1 = __ballot((b & 2u) != 0u);                                       \
    ull m2 = __ballot((b & 4u) != 0u);                                       \
    ull m3 = __ballot((b & 8u) != 0u);                                       \
    ull m4 = __ballot((b & 16u) != 0u);                                      \
    ull m5 = __ballot((b & 32u) != 0u);                                      \
    ull m6 = __ballot((b & 64u) != 0u);                                      \
    ull m7 = __ballot((b & 128u) != 0u);                                     \
    ull mp = __ballot(isp);                                                  \
    ull sel = (m0 ^ ne0) & (m1 ^ ne1) & (m2 ^ ne2) &                         \
              (m3 ^ ne3) & (m4 ^ ne4) & (m5 ^ ne5);                          \
    ull an = sel & ~mp;                                                      \
    ull ap = sel & mp;                                                       \
    ull q0 = ~m6 & ~m7, q1 = m6 & ~m7, q2 = ~m6 & m7, q3 = m6 & m7;          \
    cn0 += (uint)__popcll(an & q0); cn1 += (uint)__popcll(an & q1);          \
    cn2 += (uint)__popcll(an & q2); cn3 += (uint)__popcll(an & q3);          \
    cp0 += (uint)__popcll(ap & q0); cp1 += (uint)__popcll(ap & q1);          \
    cp2 += (uint)__popcll(ap & q2); cp3 += (uint)__popcll(ap & q3); }

    for (int i = 0; i < iters; ++i) {
        int b0 = i * 4 * G + g;
        int j0 = b0, j1 = b0 + G, j2 = b0 + 2 * G, j3 = b0 + 3 * G;
        bool v0 = j0 < n4, v1 = j1 < n4, v2 = j2 < n4, v3 = j3 < n4;
        int a0 = v0 ? j0 : n4 - 1, a1 = v1 ? j1 : n4 - 1;
        int a2 = v2 ? j2 : n4 - 1, a3 = v3 ? j3 : n4 - 1;
        // issue all 8 loads before consuming (MLP)
        float4 x0 = L4[a0], x1 = L4[a1], x2 = L4[a2], x3 = L4[a3];
        float4 t0 = T4[a0], t1 = T4[a1], t2 = T4[a2], t3 = T4[a3];
        SLOT(x0.x, t0.x, v0) SLOT(x0.y, t0.y, v0)
        SLOT(x0.z, t0.z, v0) SLOT(x0.w, t0.w, v0)
        SLOT(x1.x, t1.x, v1) SLOT(x1.y, t1.y, v1)
        SLOT(x1.z, t1.z, v1) SLOT(x1.w, t1.w, v1)
        SLOT(x2.x, t2.x, v2) SLOT(x2.y, t2.y, v2)
        SLOT(x2.z, t2.z, v2) SLOT(x2.w, t2.w, v2)
        SLOT(x3.x, t3.x, v3) SLOT(x3.y, t3.y, v3)
        SLOT(x3.z, t3.z, v3) SLOT(x3.w, t3.w, v3)
    }
#undef SLOT

    // flush this wave's register histogram: 8 LDS atomics per lane TOTAL
    atomicAdd(&hist[lane],             cn0);
    atomicAdd(&hist[lane + 64],        cn1);
    atomicAdd(&hist[lane + 128],       cn2);
    atomicAdd(&hist[lane + 192],       cn3);
    atomicAdd(&hist[256 + lane],       cp0);
    atomicAdd(&hist[256 + lane + 64],  cp1);
    atomicAdd(&hist[256 + lane + 128], cp2);
    atomicAdd(&hist[256 + lane + 192], cp3);
    __syncthreads();

    uint* dst = g_part + (size_t)blockIdx.x * NBT;
    dst[tid] = hist[tid];
    dst[tid + 256] = hist[tid + 256];
}

extern "C" __global__ __launch_bounds__(256) void ohem_reduce(
    const uint* __restrict__ g_part, uint* __restrict__ g_hist, int nb)
{
    __shared__ uint sh[256];
    int t = threadIdx.x;
    int bin = blockIdx.x * 8 + (t & 7);   // 64 blocks x 8 bins = 512
    uint s = 0;
    for (int c = (t >> 3); c < nb; c += 32)
        s += g_part[(size_t)c * NBT + bin];
    sh[t] = s;
    __syncthreads();
    #pragma unroll
    for (int off = 128; off >= 8; off >>= 1) {
        if (t < off) sh[t] += sh[t + off];
        __syncthreads();
    }
    if (t < 8) g_hist[bin] = sh[t];
}

__device__ __forceinline__ float softplus_f(float v) {
    return fmaxf(v, 0.0f) + log1pf(expf(-fabsf(v)));
}

extern "C" __global__ __launch_bounds__(256) void ohem_finalize(
    const uint* __restrict__ g_hist, float* __restrict__ out,
    int n_total, int n_pad)
{
    __shared__ uint sc[256];
    __shared__ float sl[256];
    __shared__ uint spc[256];
    __shared__ float sps[256];
    __shared__ uint suf_c[256];
    __shared__ float suf_s[256];
    __shared__ uint s_npos;
    __shared__ float s_psum;

    int t = threadIdx.x;
    uint c = g_hist[t];
    if (t == 0) c -= (uint)n_pad;         // padded lanes were forced to bin 0
    float center = ((float)t + 0.5f) * INVB - XOFF;
    sc[t] = c;
    sl[t] = c ? (float)c * softplus_f(center) : 0.0f;
    uint pc = g_hist[NBN + t];
    spc[t] = pc;
    sps[t] = pc ? (float)pc * softplus_f(-center) : 0.0f;
    __syncthreads();

    if (t == 0) {
        uint rc = 0; float rs = 0.0f;
        for (int i = 255; i >= 0; --i) {  // exclusive suffix totals
            suf_c[i] = rc; suf_s[i] = rs;
            rc += sc[i]; rs += sl[i];
        }
        uint qc = 0; float qs = 0.0f;
        for (int i = 0; i < 256; ++i) { qc += spc[i]; qs += sps[i]; }
        s_npos = qc; s_psum = qs;
    }
    __syncthreads();

    uint n_pos = s_npos;
    uint n_neg = (uint)n_total - n_pos;
    float pos_mean = n_pos ? (s_psum / (float)n_pos) : 0.0f;

    if (n_neg == 0) {
        if (t == 0) out[0] = pos_mean;
        return;
    }

    // k = max(1024, rint(0.1 * n_neg)), clamp to n_neg (RNE = jnp.round)
    float nf = (float)n_neg;
    int k = (int)rintf(nf * 0.1f);
    if (k < 1024) k = 1024;
    if ((uint)k > n_neg) k = (int)n_neg;

    // exactly one thread's bin straddles the k-th element
    uint runc = suf_c[t];
    uint cc = sc[t];
    if (cc > 0 && runc < (uint)k && runc + cc >= (uint)k) {
        uint m = (uint)k - runc;
        float nsum = suf_s[t] + (float)m * (sl[t] / (float)cc);
        out[0] = pos_mean + nsum / (float)k;
    }
}

extern "C" void kernel_launch(void* const* d_in, const int* in_sizes, int n_in,
                              void* d_out, int out_size, void* d_ws, size_t ws_size,
                              hipStream_t stream) {
    const float4* L4 = (const float4*)d_in[0];
    const float4* T4 = (const float4*)d_in[1];
    float* out = (float*)d_out;
    int n_total = in_sizes[0];
    int n4 = n_total / 4;                 // shape guarantees %4 == 0

    const int G = GRID1 * THREADS1;       // 442368 threads
    int per_iter = 4 * G;                 // float4 consumed per iteration
    int iters = (n4 + per_iter - 1) / per_iter;   // = 4 exactly for this shape
    long long E = (long long)iters * per_iter * 4;
    int n_pad = (int)(E - (long long)n_total);

    uint* g_part = (uint*)d_ws;                        // GRID1 * 512 u32
    uint* g_hist = g_part + (size_t)GRID1 * NBT;       // 512 u32

    ohem_pass1<<<GRID1, THREADS1, 0, stream>>>(L4, T4, g_part, n4, iters, G);
    ohem_reduce<<<NBT / 8, 256, 0, stream>>>(g_part, g_hist, GRID1);
    ohem_finalize<<<1, 256, 0, stream>>>(g_hist, out, n_total, n_pad);
}

// Round 7
// 77.789 us; speedup vs baseline: 1.6183x; 1.1850x over previous
//
#include <hip/hip_runtime.h>
#include <hip/hip_bf16.h>
#include <math.h>

// OHEM BCE-with-logits, (4,1,192,192,192) f32 -> scalar f32.
//
// R7: sampled-threshold + direct accumulation. No per-element LDS/DS ops.
//  A  : 1/64 coalesced-sampled 1024-bin histogram of negative logits (~3.5MB)
//  A2 : walk histogram -> threshold thr at estimated rank k (error ~13K ranks)
//  B  : full 226MB pass, 4 register accumulators/lane:
//       n_pos, pos_sum=softplus(-x), acnt=#(neg & x>=thr), asum=sum softplus
//  C  : neg_sum = asum + (k - acnt)*softplus(thr); out = pos_mean + neg_sum/k
//       boundary-rank approximation error ~1e-5 << 5.5e-2 tolerance.

typedef unsigned int uint;

#define NBIN_A 1024
#define XMINF  -8.0f
#define ASCALE 64.0f      // (x+8)*64 -> [0,1024)
#define INV_ASCALE 0.015625f
#define N4_TOTAL 7077888  // 28311552/4

__device__ __forceinline__ float softplus_f(float v) {
    return fmaxf(v, 0.0f) + log1pf(expf(-fabsf(v)));
}

// ---- A: sampled histogram (1/64 of data, coalesced 1KB chunks) ----
extern "C" __global__ __launch_bounds__(256) void ohem_sample(
    const float4* __restrict__ L4, const float4* __restrict__ T4,
    uint* __restrict__ g_hist, uint* __restrict__ g_nneg)
{
    __shared__ uint h[NBIN_A];
    __shared__ uint s_cnt[4];
    int tid = threadIdx.x;
    for (int i = tid; i < NBIN_A; i += 256) h[i] = 0u;
    __syncthreads();

    int gid = blockIdx.x * 256 + tid;
    int wave = gid >> 6, lane = gid & 63;
    size_t g = (size_t)wave * 4096 + lane;     // wave < 1728 -> g < 7077888
    float4 x4 = L4[g];
    float4 t4 = T4[g];
    float xs[4] = {x4.x, x4.y, x4.z, x4.w};
    float ts[4] = {t4.x, t4.y, t4.z, t4.w};
    uint nneg = 0;
    #pragma unroll
    for (int j = 0; j < 4; ++j) {
        if (ts[j] <= 0.5f) {
            nneg++;
            float f = fmaxf(fmaf(xs[j], ASCALE, -XMINF * ASCALE), 0.0f);
            uint b = (uint)f;
            b = b > (NBIN_A - 1) ? (NBIN_A - 1) : b;
            atomicAdd(&h[b], 1u);
        }
    }
    __syncthreads();
    for (int i = tid; i < NBIN_A; i += 256) {
        uint c = h[i];
        if (c) atomicAdd(&g_hist[i], c);
    }
    #pragma unroll
    for (int off = 32; off > 0; off >>= 1) nneg += __shfl_down(nneg, off);
    if ((tid & 63) == 0) s_cnt[tid >> 6] = nneg;
    __syncthreads();
    if (tid == 0) {
        uint c = s_cnt[0] + s_cnt[1] + s_cnt[2] + s_cnt[3];
        if (c) atomicAdd(g_nneg, c);
    }
}

// ---- A2: derive threshold from sampled histogram ----
extern "C" __global__ __launch_bounds__(256) void ohem_thresh(
    const uint* __restrict__ g_hist, const uint* __restrict__ g_nneg,
    float* __restrict__ g_thr)
{
    __shared__ uint sh_c[256];
    __shared__ uint suf[256];
    __shared__ float s_thr;
    __shared__ float s_ks;
    int t = threadIdx.x;
    uint lc[4];
    uint tc = 0;
    #pragma unroll
    for (int j = 0; j < 4; ++j) { lc[j] = g_hist[t * 4 + j]; tc += lc[j]; }
    sh_c[t] = tc;
    __syncthreads();
    if (t == 0) {
        uint rc = 0;
        for (int i = 255; i >= 0; --i) { suf[i] = rc; rc += sh_c[i]; }
        float nneg64 = 64.0f * (float)(*g_nneg);    // estimated n_neg
        float kest = rintf(0.1f * nneg64);
        if (kest < 1024.0f) kest = 1024.0f;
        s_ks = kest * 0.015625f;                    // sampled-scale target
        s_thr = XMINF;                              // fallback: select all
    }
    __syncthreads();
    float ks = s_ks;
    float run = (float)suf[t];
    #pragma unroll
    for (int j = 3; j >= 0; --j) {
        float c = (float)lc[j];
        if (c > 0.0f && run < ks && run + c >= ks)  // exactly one (t,j) fires
            s_thr = XMINF + (float)(t * 4 + j) * INV_ASCALE;  // lower bin edge
        run += c;
    }
    __syncthreads();
    if (t == 0) *g_thr = s_thr;
}

// ---- B: main pass, register accumulators only ----
extern "C" __global__ __launch_bounds__(1024) void ohem_main(
    const float4* __restrict__ L4, const float4* __restrict__ T4,
    const float* __restrict__ g_thr,
    uint* __restrict__ g_pcnt, float* __restrict__ g_psum,
    uint* __restrict__ g_acnt, float* __restrict__ g_asum,
    int n8)
{
    __shared__ uint s_pc[16];
    __shared__ float s_ps[16];
    __shared__ uint s_ac[16];
    __shared__ float s_as[16];

    const float thr = *g_thr;
    uint pcnt = 0, acnt = 0;
    float psum = 0.0f, asum = 0.0f;
    const int stride = gridDim.x * blockDim.x;

    for (int i = blockIdx.x * blockDim.x + threadIdx.x; i < n8; i += stride) {
        float4 xa = L4[2 * i];
        float4 xb = L4[2 * i + 1];
        float4 ta = T4[2 * i];
        float4 tb = T4[2 * i + 1];
        float xs[8] = {xa.x, xa.y, xa.z, xa.w, xb.x, xb.y, xb.z, xb.w};
        float ts[8] = {ta.x, ta.y, ta.z, ta.w, tb.x, tb.y, tb.z, tb.w};
        #pragma unroll
        for (int j = 0; j < 8; ++j) {
            float x = xs[j];
            float sp = fmaxf(x, 0.0f) + __logf(1.0f + __expf(-fabsf(x)));
            bool pos = ts[j] > 0.5f;
            bool sel = (x >= thr) && !pos;
            pcnt += pos ? 1u : 0u;
            psum += pos ? (sp - x) : 0.0f;   // softplus(-x) = softplus(x) - x
            acnt += sel ? 1u : 0u;
            asum += sel ? sp : 0.0f;
        }
    }

    #pragma unroll
    for (int off = 32; off > 0; off >>= 1) {
        pcnt += __shfl_down(pcnt, off);
        psum += __shfl_down(psum, off);
        acnt += __shfl_down(acnt, off);
        asum += __shfl_down(asum, off);
    }
    int wave = threadIdx.x >> 6;
    if ((threadIdx.x & 63) == 0) {
        s_pc[wave] = pcnt; s_ps[wave] = psum;
        s_ac[wave] = acnt; s_as[wave] = asum;
    }
    __syncthreads();
    if (threadIdx.x == 0) {
        uint pc = 0, ac = 0; float ps = 0.0f, as = 0.0f;
        #pragma unroll
        for (int w = 0; w < 16; ++w) {
            pc += s_pc[w]; ps += s_ps[w]; ac += s_ac[w]; as += s_as[w];
        }
        if (pc) atomicAdd(g_pcnt, pc);
        atomicAdd(g_psum, ps);
        if (ac) atomicAdd(g_acnt, ac);
        atomicAdd(g_asum, as);
    }
}

// ---- C: finalize scalar ----
extern "C" __global__ void ohem_final(
    const uint* __restrict__ g_pcnt, const float* __restrict__ g_psum,
    const uint* __restrict__ g_acnt, const float* __restrict__ g_asum,
    const float* __restrict__ g_thr, float* __restrict__ out, int n_total)
{
    if (threadIdx.x == 0 && blockIdx.x == 0) {
        uint npos = *g_pcnt;
        uint nneg = (uint)n_total - npos;
        float pos_mean = npos ? (*g_psum / (float)npos) : 0.0f;
        float res;
        if (nneg == 0) {
            res = pos_mean;
        } else {
            float nf = (float)nneg;              // RNE, matches .astype(f32)
            float kf = rintf(0.1f * nf);         // RNE, matches jnp.round
            if (kf < 1024.0f) kf = 1024.0f;
            if (kf > nf) kf = nf;
            float thr = *g_thr;
            float spt = softplus_f(thr);
            // boundary correction: works for both acnt<k and acnt>k
            float neg_sum = *g_asum + (kf - (float)(*g_acnt)) * spt;
            res = pos_mean + neg_sum / kf;
        }
        out[0] = res;
    }
}

extern "C" void kernel_launch(void* const* d_in, const int* in_sizes, int n_in,
                              void* d_out, int out_size, void* d_ws, size_t ws_size,
                              hipStream_t stream) {
    const float4* L4 = (const float4*)d_in[0];
    const float4* T4 = (const float4*)d_in[1];
    float* out = (float*)d_out;
    int n_total = in_sizes[0];
    int n8 = n_total / 8;

    // ws layout (bytes): hist[1024] @0, nneg @4096, thr @4100,
    //                    pcnt @4104, psum @4108, acnt @4112, asum @4116
    uint*  g_hist = (uint*)d_ws;
    uint*  g_nneg = (uint*)((char*)d_ws + 4096);
    float* g_thr  = (float*)((char*)d_ws + 4100);
    uint*  g_pcnt = (uint*)((char*)d_ws + 4104);
    float* g_psum = (float*)((char*)d_ws + 4108);
    uint*  g_acnt = (uint*)((char*)d_ws + 4112);
    float* g_asum = (float*)((char*)d_ws + 4116);

    hipMemsetAsync(d_ws, 0, 4120, stream);

    ohem_sample<<<432, 256, 0, stream>>>(L4, T4, g_hist, g_nneg);
    ohem_thresh<<<1, 256, 0, stream>>>(g_hist, g_nneg, g_thr);
    ohem_main<<<512, 1024, 0, stream>>>(L4, T4, g_thr,
                                        g_pcnt, g_psum, g_acnt, g_asum, n8);
    ohem_final<<<1, 64, 0, stream>>>(g_pcnt, g_psum, g_acnt, g_asum,
                                     g_thr, out, n_total);
}